// Round 5
// baseline (832.204 us; speedup 1.0000x reference)
//
#include <hip/hip_runtime.h>
#include <stdint.h>

#define SEQ  20
#define H1   128
#define H2   256
#define NCLS 100000

typedef short s16x8 __attribute__((ext_vector_type(8)));

__device__ __forceinline__ float bfval(uint16_t h) {
    union { uint32_t u; float f; } v; v.u = ((uint32_t)h) << 16; return v.f;
}
__device__ __forceinline__ uint16_t f2bf_u(float f) {
    union { uint32_t u; float f; } v; v.f = f;
    uint32_t r = (v.u + 0x7FFFu + ((v.u >> 16) & 1u)) >> 16;
    return (uint16_t)r;
}
__device__ __forceinline__ float bf2f_lo(uint32_t u) {
    union { uint32_t u; float f; } v; v.u = u << 16; return v.f;
}
__device__ __forceinline__ float bf2f_hi(uint32_t u) {
    union { uint32_t u; float f; } v; v.u = u & 0xFFFF0000u; return v.f;
}
__device__ __forceinline__ uint32_t packbf(float a, float b) {
    return ((uint32_t)f2bf_u(b) << 16) | (uint32_t)f2bf_u(a);
}
__device__ __forceinline__ float sigm(float x) { return 1.0f / (1.0f + __expf(-x)); }
__device__ __forceinline__ float tanhfast(float x) {
    float e = __expf(-2.0f * fabsf(x));
    float t = (1.0f - e) / (1.0f + e);
    return copysignf(t, x);
}

// Runtime input-dtype probe (verified round 3≡4: selects fp32 on this rig).
__device__ __forceinline__ bool probe_bf16(const void* bih) {
    const uint16_t* p = (const uint16_t*)bih;
    bool ok = true;
#pragma unroll
    for (int e = 0; e < 16; ++e) {
        float v = bfval(p[2 * e]);
        ok = ok && (fabsf(v) <= 0.25f);
    }
    return ok;
}
__device__ __forceinline__ float gld(const void* p, int i, bool bf) {
    return bf ? bfval(((const uint16_t*)p)[i]) : ((const float*)p)[i];
}

// ---------------------------------------------------------------------------
// Layer-1 LSTM (VALU). block 0 = fwd, block 1 = bwd. One gate row / thread.
// ---------------------------------------------------------------------------
__global__ __launch_bounds__(512, 2) void k_l1_v(
    const void* __restrict__ x,
    const void* __restrict__ h0f, const void* __restrict__ c0f,
    const void* __restrict__ h0b, const void* __restrict__ c0b,
    const void* __restrict__ WihF, const void* __restrict__ WhhF,
    const void* __restrict__ bihF, const void* __restrict__ bhhF,
    const void* __restrict__ WihB, const void* __restrict__ WhhB,
    const void* __restrict__ bihB, const void* __restrict__ bhhB,
    float* __restrict__ comb)           // [SEQ][H2] fp32 (ws)
{
    const int dir = blockIdx.x;
    const void* Wih = dir ? WihB : WihF;
    const void* Whh = dir ? WhhB : WhhF;
    const void* bih = dir ? bihB : bihF;
    const void* bhh = dir ? bhhB : bhhF;
    const void* h0  = dir ? h0b  : h0f;
    const void* c0  = dir ? c0b  : c0f;
    const bool bf = probe_bf16(bihF);

    __shared__ float gx[4 * H1][SEQ];
    __shared__ float hcur[H1];
    __shared__ float gall[4 * H1];

    const int j = threadIdx.x;          // gate row 0..511

    // pack Whh row j into bf16 hi/lo pairs (near-fp32 precision)
    uint32_t whi[64], wlo[64];
    if (bf) {
        const uint16_t* wp = (const uint16_t*)Whh + j * H1;
#pragma unroll
        for (int p = 0; p < 64; ++p) {
            whi[p] = ((uint32_t)wp[2 * p + 1] << 16) | wp[2 * p];
            wlo[p] = 0u;
        }
    } else {
        const float* wp = (const float*)Whh + j * H1;
#pragma unroll
        for (int p = 0; p < 64; ++p) {
            float w0 = wp[2 * p], w1 = wp[2 * p + 1];
            uint16_t a0 = f2bf_u(w0), a1 = f2bf_u(w1);
            whi[p] = ((uint32_t)a1 << 16) | a0;
            wlo[p] = packbf(w0 - bfval(a0), w1 - bfval(a1));
        }
    }

    float bias = gld(bih, j, bf) + gld(bhh, j, bf);
    for (int t = 0; t < SEQ; ++t) {
        int tx = dir ? (SEQ - 1 - t) : t;
        float a = bias;
        if (bf) {
            const uint16_t* xp = (const uint16_t*)x + tx * H1;
            const uint16_t* wp = (const uint16_t*)Wih + j * H1;
            for (int k = 0; k < H1; ++k) a += bfval(wp[k]) * bfval(xp[k]);
        } else {
            const float* xp = (const float*)x + tx * H1;
            const float* wp = (const float*)Wih + j * H1;
            for (int k = 0; k < H1; k += 4) {
                float4 xv = *(const float4*)(xp + k);
                float4 wv = *(const float4*)(wp + k);
                a += wv.x * xv.x + wv.y * xv.y + wv.z * xv.z + wv.w * xv.w;
            }
        }
        gx[j][t] = a;
    }

    float cst = 0.0f;
    if (j < H1) { hcur[j] = gld(h0, j, bf); cst = gld(c0, j, bf); }
    __syncthreads();

    for (int t = 0; t < SEQ; ++t) {
        float a = gx[j][t];
#pragma unroll
        for (int p = 0; p < 64; ++p) {
            float2 hv = *(const float2*)(hcur + 2 * p);
            uint32_t uh = whi[p], ul = wlo[p];
            a += bf2f_lo(uh) * hv.x + bf2f_hi(uh) * hv.y;
            a += bf2f_lo(ul) * hv.x + bf2f_hi(ul) * hv.y;
        }
        gall[j] = a;
        __syncthreads();
        if (j < H1) {
            float gi = gall[j], gf = gall[H1 + j], gg = gall[2 * H1 + j], go = gall[3 * H1 + j];
            float cn = sigm(gf) * cst + sigm(gi) * tanhfast(gg);
            cst = cn;
            float hn = sigm(go) * tanhfast(cn);
            hcur[j] = hn;
            comb[t * H2 + dir * H1 + j] = hn;
        }
        __syncthreads();
    }
}

// ---------------------------------------------------------------------------
// Layer-2 input projections (parallel). thread = (t, gate row).
// ---------------------------------------------------------------------------
__global__ __launch_bounds__(256, 4) void k_proj2_v(
    const void* __restrict__ Wihl,
    const void* __restrict__ bihl, const void* __restrict__ bhhl,
    const void* __restrict__ probe,
    const float* __restrict__ comb, float* __restrict__ gxl)
{
    int gid = blockIdx.x * 256 + threadIdx.x;
    int t = gid >> 10, j = gid & 1023;
    if (t >= SEQ) return;
    const bool bf = probe_bf16(probe);
    const float* cp = comb + t * H2;
    float a = gld(bihl, j, bf) + gld(bhhl, j, bf);
    if (bf) {
        const uint16_t* wp = (const uint16_t*)Wihl + j * H2;
        for (int k = 0; k < H2; ++k) a += bfval(wp[k]) * cp[k];
    } else {
        const float* wp = (const float*)Wihl + j * H2;
        for (int k = 0; k < H2; k += 4) {
            float4 wv = *(const float4*)(wp + k);
            float4 cv = *(const float4*)(cp + k);
            a += wv.x * cv.x + wv.y * cv.y + wv.z * cv.z + wv.w * cv.w;
        }
    }
    gxl[t * 1024 + j] = a;
}

// ---------------------------------------------------------------------------
// Layer-2 LSTM (VALU). 1 block x 512 threads, 2 gate rows / thread.
// Whh_l packed bf16: k<228 in regs, k>=228 in LDS (62.5 KB static total).
// ---------------------------------------------------------------------------
__global__ __launch_bounds__(512, 2) void k_l2_v(
    const void* __restrict__ Whhl,
    const void* __restrict__ h0l, const void* __restrict__ c0l,
    const void* __restrict__ probe,
    const float* __restrict__ gxl, float* __restrict__ fb)
{
    __shared__ uint32_t wlds[1024 * 14];
    __shared__ float hcur[H2];
    __shared__ float gall[1024];

    const int tid = threadIdx.x;
    const int j0 = tid * 2;
    const bool bf = probe_bf16(probe);

    for (int rr = 0; rr < 2; ++rr) {
        int j = j0 + rr;
        if (bf) {
            const uint16_t* wp = (const uint16_t*)Whhl + j * H2;
            for (int p = 0; p < 14; ++p)
                wlds[j * 14 + p] = ((uint32_t)wp[228 + 2 * p + 1] << 16) | wp[228 + 2 * p];
        } else {
            const float* wp = (const float*)Whhl + j * H2;
            for (int p = 0; p < 14; ++p)
                wlds[j * 14 + p] = packbf(wp[228 + 2 * p], wp[228 + 2 * p + 1]);
        }
    }

    uint32_t wreg[228];
#pragma unroll
    for (int rr = 0; rr < 2; ++rr) {
        int j = j0 + rr;
        if (bf) {
            const uint16_t* wp = (const uint16_t*)Whhl + j * H2;
#pragma unroll
            for (int p = 0; p < 114; ++p)
                wreg[rr * 114 + p] = ((uint32_t)wp[2 * p + 1] << 16) | wp[2 * p];
        } else {
            const float* wp = (const float*)Whhl + j * H2;
#pragma unroll
            for (int p = 0; p < 114; ++p)
                wreg[rr * 114 + p] = packbf(wp[2 * p], wp[2 * p + 1]);
        }
    }

    float cst = 0.0f;
    if (tid < H2) { hcur[tid] = gld(h0l, tid, bf); cst = gld(c0l, tid, bf); }
    __syncthreads();

    for (int t = 0; t < SEQ; ++t) {
        float g0 = gxl[t * 1024 + j0];
        float g1 = gxl[t * 1024 + j0 + 1];
        float a0 = 0.0f, a1 = 0.0f;
#pragma unroll
        for (int p = 0; p < 114; ++p) {
            float2 hv = *(const float2*)(hcur + 2 * p);
            uint32_t u0 = wreg[p], u1 = wreg[114 + p];
            a0 += bf2f_lo(u0) * hv.x + bf2f_hi(u0) * hv.y;
            a1 += bf2f_lo(u1) * hv.x + bf2f_hi(u1) * hv.y;
        }
#pragma unroll
        for (int p = 0; p < 14; ++p) {
            float2 hv = *(const float2*)(hcur + 228 + 2 * p);
            uint32_t u0 = wlds[j0 * 14 + p], u1 = wlds[(j0 + 1) * 14 + p];
            a0 += bf2f_lo(u0) * hv.x + bf2f_hi(u0) * hv.y;
            a1 += bf2f_lo(u1) * hv.x + bf2f_hi(u1) * hv.y;
        }
        gall[j0]     = a0 + g0;
        gall[j0 + 1] = a1 + g1;
        __syncthreads();
        if (tid < H2) {
            int c = tid;
            float gi = gall[c], gf = gall[256 + c], gg = gall[512 + c], go = gall[768 + c];
            float cn = sigm(gf) * cst + sigm(gi) * tanhfast(gg);
            cst = cn;
            float hn = sigm(go) * tanhfast(cn);
            hcur[c] = hn;
            fb[t * H2 + c] = hn;
        }
        __syncthreads();
    }
}

// ---------------------------------------------------------------------------
// Output linear (VALU). Thread = one class; fb transposed in LDS.
// Output is FP32 (reference returns jnp.float32).
// ---------------------------------------------------------------------------
__global__ __launch_bounds__(256, 4) void k_out_v(
    const void* __restrict__ Wlin, const void* __restrict__ blin,
    const void* __restrict__ probe,
    const float* __restrict__ fb, float* __restrict__ out)
{
    __shared__ float fbs[H2][SEQ];
    const int tid = threadIdx.x;
    for (int t = 0; t < SEQ; ++t) fbs[tid][t] = fb[t * H2 + tid];
    __syncthreads();

    const bool bf = probe_bf16(probe);
    int n = blockIdx.x * 256 + tid;
    if (n >= NCLS) return;
    float acc[SEQ];
    float b = gld(blin, n, bf);
#pragma unroll
    for (int t = 0; t < SEQ; ++t) acc[t] = b;

    if (bf) {
        const uint16_t* wp = (const uint16_t*)Wlin + (size_t)n * H2;
        for (int k = 0; k < H2; k += 8) {
            s16x8 wv8 = *(const s16x8*)(wp + k);
            float w[8];
#pragma unroll
            for (int j2 = 0; j2 < 8; ++j2) w[j2] = bfval((uint16_t)wv8[j2]);
#pragma unroll
            for (int t = 0; t < SEQ; ++t) {
                float s = 0.0f;
#pragma unroll
                for (int j2 = 0; j2 < 8; ++j2) s += w[j2] * fbs[k + j2][t];
                acc[t] += s;
            }
        }
    } else {
        const float* wp = (const float*)Wlin + (size_t)n * H2;
        for (int k = 0; k < H2; k += 4) {
            float4 wv = *(const float4*)(wp + k);
#pragma unroll
            for (int t = 0; t < SEQ; t += 4) {
                float4 f0 = *(const float4*)(&fbs[k][t]);
                float4 f1 = *(const float4*)(&fbs[k + 1][t]);
                float4 f2 = *(const float4*)(&fbs[k + 2][t]);
                float4 f3 = *(const float4*)(&fbs[k + 3][t]);
                acc[t]     += wv.x * f0.x + wv.y * f1.x + wv.z * f2.x + wv.w * f3.x;
                acc[t + 1] += wv.x * f0.y + wv.y * f1.y + wv.z * f2.y + wv.w * f3.y;
                acc[t + 2] += wv.x * f0.z + wv.y * f1.z + wv.z * f2.z + wv.w * f3.z;
                acc[t + 3] += wv.x * f0.w + wv.y * f1.w + wv.z * f2.w + wv.w * f3.w;
            }
        }
    }
#pragma unroll
    for (int t = 0; t < SEQ; ++t)
        out[(size_t)t * NCLS + n] = acc[t];
}

// ---------------------------------------------------------------------------
extern "C" void kernel_launch(void* const* d_in, const int* in_sizes, int n_in,
                              void* d_out, int out_size, void* d_ws, size_t ws_size,
                              hipStream_t stream)
{
    const void* x    = d_in[0];
    const void* h0f_ = d_in[1];
    const void* c0f_ = d_in[2];
    const void* h0b_ = d_in[3];
    const void* c0b_ = d_in[4];
    const void* h0l_ = d_in[5];
    const void* c0l_ = d_in[6];
    const void* WihF = d_in[7];
    const void* WhhF = d_in[8];
    const void* bihF = d_in[9];
    const void* bhhF = d_in[10];
    const void* WihB = d_in[11];
    const void* WhhB = d_in[12];
    const void* bihB = d_in[13];
    const void* bhhB = d_in[14];
    const void* Wihl = d_in[15];
    const void* Whhl = d_in[16];
    const void* bihl = d_in[17];
    const void* bhhl = d_in[18];
    const void* Wlin = d_in[19];
    const void* blin = d_in[20];

    float* comb = (float*)d_ws;                        // [20][256] f32
    float* gxl  = (float*)((char*)d_ws + 20480);       // [20][1024] f32
    float* fb   = (float*)((char*)d_ws + 102400);      // [20][256] f32

    k_l1_v<<<2, 512, 0, stream>>>(x, h0f_, c0f_, h0b_, c0b_,
                                  WihF, WhhF, bihF, bhhF,
                                  WihB, WhhB, bihB, bhhB, comb);
    k_proj2_v<<<80, 256, 0, stream>>>(Wihl, bihl, bhhl, bihF, comb, gxl);
    k_l2_v<<<1, 512, 0, stream>>>(Whhl, h0l_, c0l_, bihF, gxl, fb);
    k_out_v<<<391, 256, 0, stream>>>(Wlin, blin, bihF, fb, (float*)d_out);
}

// Round 6
// 362.950 us; speedup vs baseline: 2.2929x; 2.2929x over previous
//
#include <hip/hip_runtime.h>
#include <stdint.h>

#define SEQ  20
#define H1   128
#define H2   256
#define NCLS 100000

__device__ __forceinline__ float sigm(float x) { return 1.0f / (1.0f + __expf(-x)); }
__device__ __forceinline__ float tanhfast(float x) {
    float e = __expf(-2.0f * fabsf(x));
    float t = (1.0f - e) / (1.0f + e);
    return copysignf(t, x);
}

// Grid barrier across co-resident blocks: arrive (release) + spin (acquire).
// Counter zeroed by hipMemsetAsync before launch; targets are cumulative.
__device__ __forceinline__ void gbar(int* cnt, int target) {
    __syncthreads();
    if (threadIdx.x == 0) {
        __hip_atomic_fetch_add(cnt, 1, __ATOMIC_ACQ_REL, __HIP_MEMORY_SCOPE_AGENT);
        while (__hip_atomic_load(cnt, __ATOMIC_ACQUIRE, __HIP_MEMORY_SCOPE_AGENT) < target)
            __builtin_amdgcn_s_sleep(2);
    }
    __syncthreads();
}

// ---------------------------------------------------------------------------
// Layer-1 LSTM distributed: 16 blocks = 2 dirs x 8 shards. Block owns 16
// cells -> 64 gate rows x 128 cols fp32 in LDS (stride 129, 2-way bank
// aliasing = free). One device barrier per step per direction.
// ---------------------------------------------------------------------------
__global__ __launch_bounds__(256, 1) void k_l1g(
    const float* __restrict__ x,
    const float* __restrict__ h0f, const float* __restrict__ c0f,
    const float* __restrict__ h0b, const float* __restrict__ c0b,
    const float* __restrict__ WihF, const float* __restrict__ WhhF,
    const float* __restrict__ bihF, const float* __restrict__ bhhF,
    const float* __restrict__ WihB, const float* __restrict__ WhhB,
    const float* __restrict__ bihB, const float* __restrict__ bhhB,
    float* __restrict__ comb,      // [SEQ][H2] ws (plain, consumed next kernel)
    float* __restrict__ hg,        // [2][H1] ws (agent-scope exchange)
    int* __restrict__ sync)        // sync[0], sync[1]
{
    const int b   = blockIdx.x;
    const int dir = b >> 3, sub = b & 7;
    const float* Wih = dir ? WihB : WihF;
    const float* Whh = dir ? WhhB : WhhF;
    const float* bih = dir ? bihB : bihF;
    const float* bhh = dir ? bhhB : bhhF;
    const float* h0  = dir ? h0b  : h0f;
    const float* c0  = dir ? c0b  : c0f;

    __shared__ float whhS[64 * 129];    // 33024 B
    __shared__ float gxs[64][SEQ];      // 5120 B
    __shared__ float xs[H1];            // 512 B
    __shared__ float partial[4 * 64];   // 1024 B
    __shared__ float hcur[H1];          // 512 B
    __shared__ float gv[64];            // 256 B

    const int tid = threadIdx.x;
    const int lr  = tid & 63;           // local gate row 0..63 ([i16|f16|g16|o16])
    const int q   = tid >> 6;           // k-chunk 0..3 (32 cols each)
    // global row for local row L: (L>>4)*H1 + sub*16 + (L&15)

    float biasv = 0.0f;
    if (tid < 64) {
        int R = (tid >> 4) * H1 + sub * 16 + (tid & 15);
        biasv = bih[R] + bhh[R];
    }
    {   // stage Whh shard: thread -> row tid>>2, 32-col segment tid&3
        int r2 = tid >> 2, sg = tid & 3;
        int R = (r2 >> 4) * H1 + sub * 16 + (r2 & 15);
        const float* src = Whh + R * H1 + sg * 32;
        float* dst = whhS + r2 * 129 + sg * 32;
        for (int i = 0; i < 32; ++i) dst[i] = src[i];
    }
    if (tid < H1) hcur[tid] = h0[tid];
    float cst = 0.0f;
    if (tid < 16) cst = c0[sub * 16 + tid];
    __syncthreads();

    // ---- parallel prologue: gxs[lr][t] = bias + Wih[R]·x[t'] ----
    for (int t = 0; t < SEQ; ++t) {
        int tx = dir ? (SEQ - 1 - t) : t;
        if (tid < H1) xs[tid] = x[tx * H1 + tid];
        __syncthreads();
        {
            int R = (lr >> 4) * H1 + sub * 16 + (lr & 15);
            const float* wp = Wih + R * H1 + q * 32;
            const float* xp = xs + q * 32;
            float a = 0.0f;
#pragma unroll
            for (int k = 0; k < 32; k += 4) {
                float4 wv = *(const float4*)(wp + k);
                a += wv.x * xp[k] + wv.y * xp[k + 1] + wv.z * xp[k + 2] + wv.w * xp[k + 3];
            }
            partial[q * 64 + lr] = a;
        }
        __syncthreads();
        if (tid < 64)
            gxs[tid][t] = biasv + partial[tid] + partial[64 + tid]
                        + partial[128 + tid] + partial[192 + tid];
        __syncthreads();
    }

    // ---- serial recurrence, one device barrier per step ----
    for (int t = 0; t < SEQ; ++t) {
        {
            const float* wp = whhS + lr * 129 + q * 32;
            const float* hp = hcur + q * 32;
            float a = 0.0f;
#pragma unroll
            for (int k = 0; k < 32; ++k) a += wp[k] * hp[k];
            partial[q * 64 + lr] = a;
        }
        __syncthreads();
        if (tid < 64)
            gv[tid] = gxs[tid][t] + partial[tid] + partial[64 + tid]
                    + partial[128 + tid] + partial[192 + tid];
        __syncthreads();
        if (tid < 16) {
            float gi = gv[tid], gf = gv[16 + tid], gg = gv[32 + tid], go = gv[48 + tid];
            float cn = sigm(gf) * cst + sigm(gi) * tanhfast(gg);
            cst = cn;
            float hn = sigm(go) * tanhfast(cn);
            comb[t * H2 + dir * H1 + sub * 16 + tid] = hn;
            __hip_atomic_store(&hg[dir * H1 + sub * 16 + tid], hn,
                               __ATOMIC_RELEASE, __HIP_MEMORY_SCOPE_AGENT);
        }
        gbar(&sync[dir], 8 * (t + 1));
        if (tid < H1)
            hcur[tid] = __hip_atomic_load(&hg[dir * H1 + tid],
                                          __ATOMIC_RELAXED, __HIP_MEMORY_SCOPE_AGENT);
        __syncthreads();
    }
}

// ---------------------------------------------------------------------------
// Layer-2 LSTM distributed: 32 blocks, block owns 8 cells -> 32 gate rows x
// 256 cols fp32 in LDS (stride 257). Input projection folded in (prologue).
// ---------------------------------------------------------------------------
__global__ __launch_bounds__(256, 1) void k_l2g(
    const float* __restrict__ Whhl,
    const float* __restrict__ h0l, const float* __restrict__ c0l,
    const float* __restrict__ Wihl,
    const float* __restrict__ bihl, const float* __restrict__ bhhl,
    const float* __restrict__ comb,
    float* __restrict__ fb,        // [SEQ][H2] ws
    float* __restrict__ hg2,       // [H2] ws
    int* __restrict__ sync)        // sync[2]
{
    const int b = blockIdx.x;      // 0..31, cells [b*8, b*8+8)
    __shared__ float whhS[32 * 257];   // 32896 B
    __shared__ float gxs[32][SEQ];     // 2560 B
    __shared__ float combt[H2];        // 1024 B
    __shared__ float partial[8 * 32];  // 1024 B
    __shared__ float hcur[H2];         // 1024 B
    __shared__ float gv[32];           // 128 B

    const int tid = threadIdx.x;
    const int lr  = tid & 31;          // local row 0..31 ([i8|f8|g8|o8])
    const int q   = tid >> 5;          // k-chunk 0..7 (32 cols each)
    const int c0  = b * 8;
    // global row for local row L: (L>>3)*H2 + c0 + (L&7)

    float biasv = 0.0f;
    if (tid < 32) {
        int R = (tid >> 3) * H2 + c0 + (tid & 7);
        biasv = bihl[R] + bhhl[R];
    }
    {   // stage Whh_l shard: thread -> row tid>>3, 32-col segment tid&7
        int r2 = tid >> 3, sg = tid & 7;
        int R = (r2 >> 3) * H2 + c0 + (r2 & 7);
        const float* src = Whhl + R * H2 + sg * 32;
        float* dst = whhS + r2 * 257 + sg * 32;
        for (int i = 0; i < 32; ++i) dst[i] = src[i];
    }
    if (tid < H2) hcur[tid] = h0l[tid];
    float cst = 0.0f;
    if (tid < 8) cst = c0l[c0 + tid];
    __syncthreads();

    // ---- parallel prologue: gxs[lr][t] = bias + Wihl[R]·comb[t] ----
    for (int t = 0; t < SEQ; ++t) {
        combt[tid] = comb[t * H2 + tid];
        __syncthreads();
        {
            int R = (lr >> 3) * H2 + c0 + (lr & 7);
            const float* wp = Wihl + R * H2 + q * 32;
            const float* cp = combt + q * 32;
            float a = 0.0f;
#pragma unroll
            for (int k = 0; k < 32; k += 4) {
                float4 wv = *(const float4*)(wp + k);
                a += wv.x * cp[k] + wv.y * cp[k + 1] + wv.z * cp[k + 2] + wv.w * cp[k + 3];
            }
            partial[q * 32 + lr] = a;
        }
        __syncthreads();
        if (tid < 32) {
            float s = biasv;
#pragma unroll
            for (int qq = 0; qq < 8; ++qq) s += partial[qq * 32 + tid];
            gxs[tid][t] = s;
        }
        __syncthreads();
    }

    // ---- serial recurrence ----
    for (int t = 0; t < SEQ; ++t) {
        {
            const float* wp = whhS + lr * 257 + q * 32;
            const float* hp = hcur + q * 32;
            float a = 0.0f;
#pragma unroll
            for (int k = 0; k < 32; ++k) a += wp[k] * hp[k];
            partial[q * 32 + lr] = a;
        }
        __syncthreads();
        if (tid < 32) {
            float s = gxs[tid][t];
#pragma unroll
            for (int qq = 0; qq < 8; ++qq) s += partial[qq * 32 + tid];
            gv[tid] = s;
        }
        __syncthreads();
        if (tid < 8) {
            float gi = gv[tid], gf = gv[8 + tid], gg = gv[16 + tid], go = gv[24 + tid];
            float cn = sigm(gf) * cst + sigm(gi) * tanhfast(gg);
            cst = cn;
            float hn = sigm(go) * tanhfast(cn);
            fb[t * H2 + c0 + tid] = hn;
            __hip_atomic_store(&hg2[c0 + tid], hn,
                               __ATOMIC_RELEASE, __HIP_MEMORY_SCOPE_AGENT);
        }
        gbar(&sync[2], 32 * (t + 1));
        hcur[tid] = __hip_atomic_load(&hg2[tid],
                                      __ATOMIC_RELAXED, __HIP_MEMORY_SCOPE_AGENT);
        __syncthreads();
    }
}

// ---------------------------------------------------------------------------
// Output linear (unchanged from round 5 except kept fp32-only).
// Thread = one class; fb transposed in LDS.
// ---------------------------------------------------------------------------
__global__ __launch_bounds__(256, 4) void k_out_v(
    const float* __restrict__ Wlin, const float* __restrict__ blin,
    const float* __restrict__ fb, float* __restrict__ out)
{
    __shared__ float fbs[H2][SEQ];
    const int tid = threadIdx.x;
    for (int t = 0; t < SEQ; ++t) fbs[tid][t] = fb[t * H2 + tid];
    __syncthreads();

    int n = blockIdx.x * 256 + tid;
    if (n >= NCLS) return;
    float acc[SEQ];
    float bv = blin[n];
#pragma unroll
    for (int t = 0; t < SEQ; ++t) acc[t] = bv;

    const float* wp = Wlin + (size_t)n * H2;
    for (int k = 0; k < H2; k += 4) {
        float4 wv = *(const float4*)(wp + k);
#pragma unroll
        for (int t = 0; t < SEQ; t += 4) {
            float4 f0 = *(const float4*)(&fbs[k][t]);
            float4 f1 = *(const float4*)(&fbs[k + 1][t]);
            float4 f2 = *(const float4*)(&fbs[k + 2][t]);
            float4 f3 = *(const float4*)(&fbs[k + 3][t]);
            acc[t]     += wv.x * f0.x + wv.y * f1.x + wv.z * f2.x + wv.w * f3.x;
            acc[t + 1] += wv.x * f0.y + wv.y * f1.y + wv.z * f2.y + wv.w * f3.y;
            acc[t + 2] += wv.x * f0.z + wv.y * f1.z + wv.z * f2.z + wv.w * f3.z;
            acc[t + 3] += wv.x * f0.w + wv.y * f1.w + wv.z * f2.w + wv.w * f3.w;
        }
    }
#pragma unroll
    for (int t = 0; t < SEQ; ++t)
        out[(size_t)t * NCLS + n] = acc[t];
}

// ---------------------------------------------------------------------------
extern "C" void kernel_launch(void* const* d_in, const int* in_sizes, int n_in,
                              void* d_out, int out_size, void* d_ws, size_t ws_size,
                              hipStream_t stream)
{
    const float* x    = (const float*)d_in[0];
    const float* h0f_ = (const float*)d_in[1];
    const float* c0f_ = (const float*)d_in[2];
    const float* h0b_ = (const float*)d_in[3];
    const float* c0b_ = (const float*)d_in[4];
    const float* h0l_ = (const float*)d_in[5];
    const float* c0l_ = (const float*)d_in[6];
    const float* WihF = (const float*)d_in[7];
    const float* WhhF = (const float*)d_in[8];
    const float* bihF = (const float*)d_in[9];
    const float* bhhF = (const float*)d_in[10];
    const float* WihB = (const float*)d_in[11];
    const float* WhhB = (const float*)d_in[12];
    const float* bihB = (const float*)d_in[13];
    const float* bhhB = (const float*)d_in[14];
    const float* Wihl = (const float*)d_in[15];
    const float* Whhl = (const float*)d_in[16];
    const float* bihl = (const float*)d_in[17];
    const float* bhhl = (const float*)d_in[18];
    const float* Wlin = (const float*)d_in[19];
    const float* blin = (const float*)d_in[20];

    char* ws = (char*)d_ws;
    int*   sync = (int*)ws;                      // 3 counters (256 B reserved)
    float* hg   = (float*)(ws + 256);            // [2][128]
    float* hg2  = (float*)(ws + 1536);           // [256]
    float* comb = (float*)(ws + 4096);           // [20][256]
    float* fb   = (float*)(ws + 24576);          // [20][256]

    hipMemsetAsync(sync, 0, 256, stream);

    k_l1g<<<16, 256, 0, stream>>>(x, h0f_, c0f_, h0b_, c0b_,
                                  WihF, WhhF, bihF, bhhF,
                                  WihB, WhhB, bihB, bhhB,
                                  comb, hg, sync);
    k_l2g<<<32, 256, 0, stream>>>(Whhl, h0l_, c0l_,
                                  Wihl, bihl, bhhl,
                                  comb, fb, hg2, sync);
    k_out_v<<<391, 256, 0, stream>>>(Wlin, blin, fb, (float*)d_out);
}